// Round 5
// baseline (704.659 us; speedup 1.0000x reference)
//
#include <hip/hip_runtime.h>
#include <hip/hip_bf16.h>
#include <stdint.h>

typedef __bf16 bf16;
typedef __bf16 bf16x8 __attribute__((ext_vector_type(8)));
typedef __bf16 bf16x4 __attribute__((ext_vector_type(4)));
typedef float f32x4 __attribute__((ext_vector_type(4)));

#define E_DIM 2048
#define HEADS 16
#define HD 128
#define SEQ 2048
#define BATCH 2
#define NTOK 4096
#define NSLOT 8

// 1/sqrt(128) * log2(e): folded into Q / TQ at projection time
#define QSCALE (0.08838834764831845f * 1.4426950408889634f)

#define WAITV(N) asm volatile("s_waitcnt vmcnt(" #N ")" ::: "memory")

__device__ __forceinline__ void gload_lds16(const void* g, void* lds) {
  __builtin_amdgcn_global_load_lds(
      (const __attribute__((address_space(1))) uint32_t*)g,
      (__attribute__((address_space(3))) uint32_t*)lds, 16, 0, 0);
}

// ---------------- f32 -> bf16 convert, 8 elems/thread, grid-stride ----------------
__global__ __launch_bounds__(256) void cvt_f32_bf16_kernel(
    const float* __restrict__ src, bf16* __restrict__ dst, int n8)
{
  for (int i = blockIdx.x * 256 + threadIdx.x; i < n8; i += gridDim.x * 256) {
    const f32x4 a = *(const f32x4*)(src + i * 8);
    const f32x4 b = *(const f32x4*)(src + i * 8 + 4);
    bf16x8 o;
#pragma unroll
    for (int j = 0; j < 4; j++) { o[j] = (bf16)a[j]; o[4 + j] = (bf16)b[j]; }
    *(bf16x8*)(dst + i * 8) = o;
  }
}

struct ProjArgs {
  const bf16* W[4];
  const float* bias[4];
  void* out[4];
  int mode[4];     // 0: f32 row-major [M][N=2048]; 1: bf16 [B,H,S,D]; 2: bf16 [B,H,D,S]
  float scale[4];  // applied AFTER bias
};

// ---------------- 256x256 NT GEMM, BK=32, 8 waves, quad-buffer counted vmcnt ----------
// C = (A @ W^T + bias)*scale. A [M][2048] bf16, W [N][2048] bf16.
// LDS 128 KiB = 4 bufs x (A[256][32] + B[256][32]) bf16. Rows are 64B;
// 16B slots XOR-swizzled: phys_slot = logical_slot ^ ((row>>1)&3)  (2-way on
// reads = free). Staged via global_load_lds (linear dest, inverse-swizzled
// global source). Prefetch depth 3 tiles (12 loads/thread in flight);
// per-iter s_waitcnt vmcnt(8) BEFORE raw s_barrier proves tile t+1 resident
// for every wave without ever draining to 0 in the main loop (T4).
__global__ __launch_bounds__(512, 2) void gemm256_kernel(
    const bf16* __restrict__ A, ProjArgs pa, int nbm, int nbn)
{
  __shared__ bf16 As[4][256 * 32];
  __shared__ bf16 Bs[4][256 * 32];

  // bijective XCD swizzle (nwg % 8 == 0), bm fastest -> per-XCD weight-panel L2 reuse
  const int nwg = gridDim.x;
  const int qch = nwg >> 3;
  const int wg = (blockIdx.x & 7) * qch + (blockIdx.x >> 3);
  const int bm = wg % nbm;
  const int rest = wg / nbm;
  const int bn = rest % nbn;
  const int z = rest / nbn;

  const bf16* __restrict__ W = pa.W[z];
  const float* __restrict__ bias = pa.bias[z];
  void* __restrict__ out = pa.out[z];
  const int mode = pa.mode[z];
  const float scale = pa.scale[z];

  const int tid = threadIdx.x;
  const int lane = tid & 63;
  const int w = tid >> 6;          // 0..7
  const int wr = w >> 2;           // 0..1 (M)
  const int wc = w & 3;            // 0..3 (N)
  const int g = lane >> 4, c = lane & 15;

  // staging map: wave w stages rows [w*32, w*32+32) of both A and B tiles.
  const int r4 = lane >> 2;                        // 0..15 row-in-16
  const int sl = lane & 3;                         // 16B slot
  const int scol = (sl ^ ((r4 >> 1) & 3)) * 8;     // inverse-swizzled source col
  const bf16* Asrc = A + (size_t)(bm * 256 + w * 32 + r4) * 2048 + scol;
  const bf16* Bsrc = W + (size_t)(bn * 256 + w * 32 + r4) * 2048 + scol;

  auto stage = [&](int t) {
    const int buf = t & 3;
    const int k0 = t * 32;
#pragma unroll
    for (int i = 0; i < 2; i++) {
      gload_lds16(Asrc + (size_t)(i * 16) * 2048 + k0,
                  (char*)(&As[buf][0]) + (w * 32 + i * 16) * 64);
      gload_lds16(Bsrc + (size_t)(i * 16) * 2048 + k0,
                  (char*)(&Bs[buf][0]) + (w * 32 + i * 16) * 64);
    }
  };

  f32x4 acc[8][4] = {};
  const int fsw = (c >> 1) & 3;    // read-side swizzle term

  stage(0); stage(1); stage(2);
  WAITV(8);                         // tile 0 landed (own loads), all waves
  __builtin_amdgcn_s_barrier();

  const int NT = 2048 / 32;         // 64
  for (int t = 0; t < NT; t++) {
    const int buf = t & 3;
    if (t + 3 < NT) stage(t + 3);   // writes buf (t-1)&3: reads done at end of t-1

    bf16x8 af[8], bfr[4];
#pragma unroll
    for (int n = 0; n < 4; n++) {
      const int row = wc * 64 + n * 16 + c;
      bfr[n] = *(const bf16x8*)((const char*)(&Bs[buf][0]) + row * 64 + ((g ^ fsw) * 16));
    }
#pragma unroll
    for (int mi = 0; mi < 8; mi++) {
      const int row = wr * 128 + mi * 16 + c;
      af[mi] = *(const bf16x8*)((const char*)(&As[buf][0]) + row * 64 + ((g ^ fsw) * 16));
    }
    __builtin_amdgcn_s_setprio(1);
#pragma unroll
    for (int mi = 0; mi < 8; mi++)
#pragma unroll
      for (int n = 0; n < 4; n++)
        acc[mi][n] = __builtin_amdgcn_mfma_f32_16x16x32_bf16(af[mi], bfr[n], acc[mi][n], 0, 0, 0);
    __builtin_amdgcn_s_setprio(0);

    // counted wait BEFORE barrier: every wave's tile t+1 loads retired when all pass
    if (t < NT - 3)       WAITV(8);
    else if (t == NT - 3) WAITV(4);
    else if (t == NT - 2) WAITV(0);
    if (t < NT - 1) __builtin_amdgcn_s_barrier();
  }

  // epilogue: D[r][c]: col = lane&15, row = (lane>>4)*4 + j  (per 16x16 frag)
#pragma unroll
  for (int mi = 0; mi < 8; mi++) {
#pragma unroll
    for (int n = 0; n < 4; n++) {
      const int col = bn * 256 + wc * 64 + n * 16 + c;
      const float bv = bias[col];
#pragma unroll
      for (int j = 0; j < 4; j++) {
        const int row = bm * 256 + wr * 128 + mi * 16 + g * 4 + j;
        const float v = (acc[mi][n][j] + bv) * scale;
        if (mode == 0) {
          ((float*)out)[(size_t)row * E_DIM + col] = v;
        } else {
          const int b = row >> 11, s = row & 2047;
          const int h = col >> 7, d = col & 127;
          size_t idx;
          if (mode == 1) idx = (((size_t)(b * HEADS + h)) * SEQ + s) * HD + d;
          else           idx = (((size_t)(b * HEADS + h)) * HD + d) * SEQ + s;
          ((bf16*)out)[idx] = (bf16)v;
        }
      }
    }
  }
}

// ---------------- slots projections: tk/tv = slots @ W^T + b, f32 [8][2048] ----------------
__global__ __launch_bounds__(256) void slots_proj_kernel(
    const float* __restrict__ slots,
    const float* __restrict__ Wk, const float* __restrict__ bk,
    const float* __restrict__ Wv, const float* __restrict__ bv,
    float* __restrict__ tk, float* __restrict__ tv)
{
  const int col = blockIdx.x * 256 + threadIdx.x;
  const int slot = blockIdx.y;
  const int mat = blockIdx.z;
  const float* W = mat ? Wv : Wk;
  const float* bias = mat ? bv : bk;
  float* out = mat ? tv : tk;
  const float* xr = slots + (size_t)slot * E_DIM;
  const float* wr = W + (size_t)col * E_DIM;
  float acc = 0.f;
  for (int k = 0; k < E_DIM; k += 4) {
    const f32x4 a = *(const f32x4*)(xr + k);
    const f32x4 b4 = *(const f32x4*)(wr + k);
#pragma unroll
    for (int i = 0; i < 4; i++) acc += a[i] * b4[i];
  }
  out[(size_t)slot * E_DIM + col] = acc + bias[col];
}

// ---------------- flash attention: barrier-free, K/V direct from L2 ----------------
// Q pre-scaled by QSCALE. Q,K: bf16 [B,H,S,D]; Vt: bf16 [B,H,D,S]; out: bf16 [B,S,E].
// 4 waves, 128 q rows (32/wave). KV tile 64. K/V fragments load straight from
// global (L2-resident: XCD swizzle keeps 4 bh ~ 4MB per XCD L2). P round-trips
// through per-wave LDS (wave-local lgkm ordering). NO __syncthreads anywhere.
__global__ __launch_bounds__(256) void flash_attn_kernel(
    const bf16* __restrict__ Qg, const bf16* __restrict__ Kg,
    const bf16* __restrict__ Vtg, bf16* __restrict__ Og)
{
  __shared__ char Ps[4][4096];        // per-wave [q32][kv64] bf16, swizzled

  const int orig = blockIdx.x;                 // 512 blocks
  const int logical = (orig & 7) * 64 + (orig >> 3);   // XCD k -> bh in [4k,4k+4)
  const int qt = logical & 15;
  const int bh = logical >> 4;

  const int tid = threadIdx.x;
  const int lane = tid & 63;
  const int w = tid >> 6;
  const int g = lane >> 4, c = lane & 15;
  const int b = bh >> 4, h = bh & 15;
  const int q0 = qt * 128 + w * 32;

  const bf16* Qb = Qg + ((size_t)bh * SEQ + q0) * HD;
  const bf16* Kb = Kg + (size_t)bh * SEQ * HD;
  const bf16* Vb = Vtg + (size_t)bh * HD * SEQ;
  char* Pw = Ps[w];

  // Q fragments (B operand), pre-scaled: qf[kk][n][j] = Q[n*16+c][kk*32+g*8+j]
  bf16x8 qf[4][2];
#pragma unroll
  for (int kk = 0; kk < 4; kk++)
#pragma unroll
    for (int n = 0; n < 2; n++)
      qf[kk][n] = *(const bf16x8*)(Qb + (size_t)(n * 16 + c) * HD + kk * 32 + g * 8);

  f32x4 acc[2][8] = {};
  float mrun[2] = {-1e30f, -1e30f};
  float lrun[2] = {0.f, 0.f};

  for (int kv0 = 0; kv0 < SEQ; kv0 += 64) {
    // S^T[kv][q] = K · Q^T  (scores in log2 domain via pre-scaled Q)
    f32x4 st[4][2] = {};
#pragma unroll
    for (int kk = 0; kk < 4; kk++) {
      bf16x8 kf[4];
#pragma unroll
      for (int kfr = 0; kfr < 4; kfr++)
        kf[kfr] = *(const bf16x8*)(Kb + (size_t)(kv0 + kfr * 16 + c) * HD + kk * 32 + g * 8);
      __builtin_amdgcn_s_setprio(1);
#pragma unroll
      for (int kfr = 0; kfr < 4; kfr++)
#pragma unroll
        for (int n = 0; n < 2; n++)
          st[kfr][n] = __builtin_amdgcn_mfma_f32_16x16x32_bf16(kf[kfr], qf[kk][n], st[kfr][n], 0, 0, 0);
      __builtin_amdgcn_s_setprio(0);
    }

    // online softmax with defer-max; lane holds kv = kfr*16+g*4+j for q = n*16+c
    float fsc[2];
    bool anyresc = false;
#pragma unroll
    for (int n = 0; n < 2; n++) {
      float lm = -1e30f;
#pragma unroll
      for (int kfr = 0; kfr < 4; kfr++)
#pragma unroll
        for (int j = 0; j < 4; j++) lm = fmaxf(lm, st[kfr][n][j]);
      lm = fmaxf(lm, __shfl_xor(lm, 16));
      lm = fmaxf(lm, __shfl_xor(lm, 32));
      if (__any(lm > mrun[n] + 8.0f)) {           // wave-uniform
        const float mn = fmaxf(mrun[n], lm);
        fsc[n] = exp2f(mrun[n] - mn);
        mrun[n] = mn;
        anyresc = true;
      } else {
        fsc[n] = 1.0f;                             // P bounded by 2^8, bf16-safe
      }
      float ps = 0.f;
#pragma unroll
      for (int kfr = 0; kfr < 4; kfr++)
#pragma unroll
        for (int j = 0; j < 4; j++) {
          const float pp = exp2f(st[kfr][n][j] - mrun[n]);
          st[kfr][n][j] = pp;
          ps += pp;
        }
      ps += __shfl_xor(ps, 16);
      ps += __shfl_xor(ps, 32);
      lrun[n] = lrun[n] * fsc[n] + ps;
    }

    if (anyresc) {
#pragma unroll
      for (int m = 0; m < 2; m++)
#pragma unroll
        for (int j = 0; j < 4; j++) {
          const float fj = __shfl(fsc[m], (lane & 48) | (g * 4 + j));
#pragma unroll
          for (int n = 0; n < 8; n++) acc[m][n][j] *= fj;
        }
    }

    // write P (bf16) to per-wave LDS [q][kv], swizzled (wave-local, no barrier)
#pragma unroll
    for (int n = 0; n < 2; n++)
#pragma unroll
      for (int kfr = 0; kfr < 4; kfr++) {
        bf16x4 pk;
#pragma unroll
        for (int j = 0; j < 4; j++) pk[j] = (bf16)st[kfr][n][j];
        const int q = n * 16 + c;
        const int L = q * 128 + kfr * 32 + g * 8;
        *(bf16x4*)(Pw + (L ^ ((q & 7) << 4))) = pk;
      }

    // O += P · V : A = P[q][kv] from LDS, B = Vt[d][kv] direct from L2
#pragma unroll
    for (int kk = 0; kk < 2; kk++) {
      bf16x8 vf[8];
#pragma unroll
      for (int n = 0; n < 8; n++)
        vf[n] = *(const bf16x8*)(Vb + (size_t)(n * 16 + c) * SEQ + kv0 + kk * 32 + g * 8);
      bf16x8 pf[2];
#pragma unroll
      for (int m = 0; m < 2; m++) {
        const int q = m * 16 + c;
        const int L = q * 128 + kk * 64 + g * 16;
        pf[m] = *(const bf16x8*)(Pw + (L ^ ((q & 7) << 4)));
      }
      __builtin_amdgcn_s_setprio(1);
#pragma unroll
      for (int n = 0; n < 8; n++)
#pragma unroll
        for (int m = 0; m < 2; m++)
          acc[m][n] = __builtin_amdgcn_mfma_f32_16x16x32_bf16(pf[m], vf[n], acc[m][n], 0, 0, 0);
      __builtin_amdgcn_s_setprio(0);
    }
  }

  // epilogue: normalize and write [B,S,E]
#pragma unroll
  for (int m = 0; m < 2; m++) {
#pragma unroll
    for (int j = 0; j < 4; j++) {
      const float lb = __shfl(lrun[m], (lane & 48) | (g * 4 + j));
      const float linv = 1.0f / lb;
      const int s = q0 + m * 16 + g * 4 + j;
#pragma unroll
      for (int n = 0; n < 8; n++) {
        const int e = h * HD + n * 16 + c;
        Og[((size_t)b * SEQ + s) * E_DIM + e] = (bf16)(acc[m][n][j] * linv);
      }
    }
  }
}

// ---------------- fused thought cross-attn + LayerNorm ----------------
__global__ __launch_bounds__(256) void thought_ln_kernel(
    const bf16* __restrict__ TQ, const float* __restrict__ TK,
    const float* __restrict__ TV, const bf16* __restrict__ ATT,
    const float* __restrict__ gamma, const float* __restrict__ beta,
    bf16* __restrict__ Y)
{
  __shared__ float wsum[4], wsq[4];
  const int tid = threadIdx.x;
  const int lane = tid & 63;
  const int w = tid >> 6;
  const int tok = blockIdx.x;            // b*SEQ + s
  const int b = tok >> 11, s = tok & 2047;
  const int e0 = tid * 8;
  const int h = e0 >> 7;
  const int d0 = e0 & 127;

  const bf16x8 av = *(const bf16x8*)(ATT + (size_t)tok * E_DIM + e0);
  float v[8];
#pragma unroll
  for (int i = 0; i < 8; i++) v[i] = (float)av[i];

  const bf16x8 qv8 = *(const bf16x8*)(TQ + (((size_t)(b * HEADS + h)) * SEQ + s) * HD + d0);
  float qv[8];
#pragma unroll
  for (int i = 0; i < 8; i++) qv[i] = (float)qv8[i];

  float dts[NSLOT];
#pragma unroll
  for (int sl = 0; sl < NSLOT; sl++) {
    const float* tkr = TK + (size_t)sl * E_DIM + e0;
    const f32x4 k0 = *(const f32x4*)(tkr);
    const f32x4 k1 = *(const f32x4*)(tkr + 4);
    float dp = 0.f;
#pragma unroll
    for (int i = 0; i < 4; i++) dp += qv[i] * k0[i] + qv[4 + i] * k1[i];
    dp += __shfl_xor(dp, 1);
    dp += __shfl_xor(dp, 2);
    dp += __shfl_xor(dp, 4);
    dp += __shfl_xor(dp, 8);
    dts[sl] = dp;
  }
  float mx = dts[0];
#pragma unroll
  for (int sl = 1; sl < NSLOT; sl++) mx = fmaxf(mx, dts[sl]);
  float p[NSLOT], den = 0.f;
#pragma unroll
  for (int sl = 0; sl < NSLOT; sl++) { p[sl] = exp2f(dts[sl] - mx); den += p[sl]; }
  const float dinv = 1.0f / den;
#pragma unroll
  for (int sl = 0; sl < NSLOT; sl++) {
    const float pn = p[sl] * dinv;
    const float* tvr = TV + (size_t)sl * E_DIM + e0;
    const f32x4 v0 = *(const f32x4*)(tvr);
    const f32x4 v1 = *(const f32x4*)(tvr + 4);
#pragma unroll
    for (int i = 0; i < 4; i++) { v[i] += pn * v0[i]; v[4 + i] += pn * v1[i]; }
  }

  float sm = 0.f, sq = 0.f;
#pragma unroll
  for (int i = 0; i < 8; i++) { sm += v[i]; sq += v[i] * v[i]; }
#pragma unroll
  for (int d = 1; d < 64; d <<= 1) { sm += __shfl_xor(sm, d); sq += __shfl_xor(sq, d); }
  if (lane == 0) { wsum[w] = sm; wsq[w] = sq; }
  __syncthreads();
  const float ts = wsum[0] + wsum[1] + wsum[2] + wsum[3];
  const float tq2 = wsq[0] + wsq[1] + wsq[2] + wsq[3];
  const float mean = ts * (1.f / E_DIM);
  const float var = tq2 * (1.f / E_DIM) - mean * mean;
  const float rstd = rsqrtf(var + 1e-5f);
  const f32x4 g0 = *(const f32x4*)(gamma + e0);
  const f32x4 g1 = *(const f32x4*)(gamma + e0 + 4);
  const f32x4 b0 = *(const f32x4*)(beta + e0);
  const f32x4 b1 = *(const f32x4*)(beta + e0 + 4);
  bf16x8 outv;
#pragma unroll
  for (int i = 0; i < 4; i++) {
    outv[i]     = (bf16)((v[i]     - mean) * rstd * g0[i] + b0[i]);
    outv[4 + i] = (bf16)((v[4 + i] - mean) * rstd * g1[i] + b1[i]);
  }
  *(bf16x8*)(Y + (size_t)tok * E_DIM + e0) = outv;
}

extern "C" void kernel_launch(void* const* d_in, const int* in_sizes, int n_in,
                              void* d_out, int out_size, void* d_ws, size_t ws_size,
                              hipStream_t stream) {
  (void)in_sizes; (void)n_in; (void)out_size; (void)ws_size;
  const float* x     = (const float*)d_in[0];
  const float* slots = (const float*)d_in[1];
  const float* Wq  = (const float*)d_in[2];   const float* bq  = (const float*)d_in[3];
  const float* Wk  = (const float*)d_in[4];   const float* bk  = (const float*)d_in[5];
  const float* Wv  = (const float*)d_in[6];   const float* bv  = (const float*)d_in[7];
  const float* Wtq = (const float*)d_in[8];   const float* btq = (const float*)d_in[9];
  const float* Wtk = (const float*)d_in[10];  const float* btk = (const float*)d_in[11];
  const float* Wtv = (const float*)d_in[12];  const float* btv = (const float*)d_in[13];
  const float* Wo  = (const float*)d_in[14];  const float* bo  = (const float*)d_in[15];
  const float* gamma = (const float*)d_in[16];
  const float* beta  = (const float*)d_in[17];

  uint8_t* ws = (uint8_t*)d_ws;
  const size_t BUF  = (size_t)NTOK * E_DIM * sizeof(bf16);    // 16 MiB (activations)
  const size_t WBUF = (size_t)E_DIM * E_DIM * sizeof(bf16);   // 8 MiB (weights)
  bf16* xb   = (bf16*)(ws + 0 * BUF);          // [B,S,E] bf16 x
  bf16* qb   = (bf16*)(ws + 1 * BUF);          // [B,H,S,D] (pre-scaled)
  bf16* kb   = (bf16*)(ws + 2 * BUF);          // [B,H,S,D]
  bf16* vtb  = (bf16*)(ws + 3 * BUF);          // [B,H,D,S]
  bf16* tqb  = (bf16*)(ws + 4 * BUF);          // [B,H,S,D] (pre-scaled)
  bf16* attb = (bf16*)(ws + 5 * BUF);          // [B,S,E] flash output
  bf16* nrmb = qb;                             // alias: qb dead after flash
  uint8_t* wp = ws + 6 * BUF;
  bf16* Wqb  = (bf16*)(wp + 0 * WBUF);
  bf16* Wkb  = (bf16*)(wp + 1 * WBUF);
  bf16* Wvb  = (bf16*)(wp + 2 * WBUF);
  bf16* Wtqb = (bf16*)(wp + 3 * WBUF);
  bf16* Wob  = (bf16*)(wp + 4 * WBUF);
  float* tkb = (float*)(wp + 5 * WBUF);               // [8][E] f32
  float* tvb = (float*)(wp + 5 * WBUF + 128 * 1024);  // [8][E] f32

  // --- convert f32 -> bf16 for MFMA consumers ---
  const int WN8 = E_DIM * E_DIM / 8;   // 524288
  const int XN8 = NTOK * E_DIM / 8;    // 1048576
  cvt_f32_bf16_kernel<<<dim3(2048), 256, 0, stream>>>(x, xb, XN8);
  cvt_f32_bf16_kernel<<<dim3(1024), 256, 0, stream>>>(Wq, Wqb, WN8);
  cvt_f32_bf16_kernel<<<dim3(1024), 256, 0, stream>>>(Wk, Wkb, WN8);
  cvt_f32_bf16_kernel<<<dim3(1024), 256, 0, stream>>>(Wv, Wvb, WN8);
  cvt_f32_bf16_kernel<<<dim3(1024), 256, 0, stream>>>(Wtq, Wtqb, WN8);
  cvt_f32_bf16_kernel<<<dim3(1024), 256, 0, stream>>>(Wo, Wob, WN8);

  // --- projections (Q and TQ pre-scaled by 1/sqrt(D)*log2e) ---
  ProjArgs pa;
  pa.W[0] = Wqb;  pa.bias[0] = bq;  pa.out[0] = qb;  pa.mode[0] = 1; pa.scale[0] = QSCALE;
  pa.W[1] = Wkb;  pa.bias[1] = bk;  pa.out[1] = kb;  pa.mode[1] = 1; pa.scale[1] = 1.0f;
  pa.W[2] = Wvb;  pa.bias[2] = bv;  pa.out[2] = vtb; pa.mode[2] = 2; pa.scale[2] = 1.0f;
  pa.W[3] = Wtqb; pa.bias[3] = btq; pa.out[3] = tqb; pa.mode[3] = 1; pa.scale[3] = QSCALE;
  gemm256_kernel<<<dim3(16 * 8 * 4), 512, 0, stream>>>(xb, pa, 16, 8);

  slots_proj_kernel<<<dim3(E_DIM / 256, NSLOT, 2), 256, 0, stream>>>(
      slots, Wtk, btk, Wtv, btv, tkb, tvb);

  // --- attention streams ---
  flash_attn_kernel<<<dim3((SEQ / 128) * BATCH * HEADS), 256, 0, stream>>>(
      qb, kb, vtb, attb);
  thought_ln_kernel<<<dim3(NTOK), 256, 0, stream>>>(
      tqb, tkb, tvb, attb, gamma, beta, nrmb);

  // --- output projection (f32 out) ---
  ProjArgs po;
  po.W[0] = Wob; po.bias[0] = bo; po.out[0] = d_out; po.mode[0] = 0; po.scale[0] = 1.0f;
  po.W[1] = po.W[2] = po.W[3] = Wob;
  po.bias[1] = po.bias[2] = po.bias[3] = bo;
  po.out[1] = po.out[2] = po.out[3] = d_out;
  po.mode[1] = po.mode[2] = po.mode[3] = 0;
  po.scale[1] = po.scale[2] = po.scale[3] = 1.0f;
  gemm256_kernel<<<dim3(16 * 8 * 1), 512, 0, stream>>>(nrmb, po, 16, 8);
}

// Round 6
// 523.876 us; speedup vs baseline: 1.3451x; 1.3451x over previous
//
#include <hip/hip_runtime.h>
#include <hip/hip_bf16.h>
#include <stdint.h>

typedef __bf16 bf16;
typedef __bf16 bf16x8 __attribute__((ext_vector_type(8)));
typedef __bf16 bf16x4 __attribute__((ext_vector_type(4)));
typedef float f32x4 __attribute__((ext_vector_type(4)));

#define E_DIM 2048
#define HEADS 16
#define HD 128
#define SEQ 2048
#define BATCH 2
#define NTOK 4096
#define NSLOT 8

// 1/sqrt(128) * log2(e): folded into Q / TQ at projection time
#define QSCALE (0.08838834764831845f * 1.4426950408889634f)

__device__ __forceinline__ void gload_lds16(const void* g, void* lds) {
  __builtin_amdgcn_global_load_lds(
      (const __attribute__((address_space(1))) uint32_t*)g,
      (__attribute__((address_space(3))) uint32_t*)lds, 16, 0, 0);
}

// ---------------- f32 -> bf16 convert, 8 elems/thread, grid-stride ----------------
__global__ __launch_bounds__(256) void cvt_f32_bf16_kernel(
    const float* __restrict__ src, bf16* __restrict__ dst, int n8)
{
  for (int i = blockIdx.x * 256 + threadIdx.x; i < n8; i += gridDim.x * 256) {
    const f32x4 a = *(const f32x4*)(src + i * 8);
    const f32x4 b = *(const f32x4*)(src + i * 8 + 4);
    bf16x8 o;
#pragma unroll
    for (int j = 0; j < 4; j++) { o[j] = (bf16)a[j]; o[4 + j] = (bf16)b[j]; }
    *(bf16x8*)(dst + i * 8) = o;
  }
}

struct ProjArgs {
  const bf16* W[4];
  const float* bias[4];
  void* out[4];
  int mode[4];     // 0: f32 row-major [M][N=2048]; 1: bf16 [B,H,S,D]; 2: bf16 [B,H,D,S]
  float scale[4];  // applied AFTER bias
};

// ---------------- 256x256 NT GEMM, BK=64, 8 waves (2M x 4N), K=2048 ----------------
// Round-4 measured-good version: 195.9us for 4 fused GEMMs, 0 bank conflicts.
__global__ __launch_bounds__(512, 2) void gemm256_kernel(
    const bf16* __restrict__ A, ProjArgs pa, int nbm, int nbn)
{
  __shared__ bf16 As[2][256 * 64];
  __shared__ bf16 Bs[2][256 * 64];

  const int nwg = gridDim.x;
  const int qch = nwg >> 3;
  const int wg = (blockIdx.x & 7) * qch + (blockIdx.x >> 3);
  const int bm = wg % nbm;
  const int rest = wg / nbm;
  const int bn = rest % nbn;
  const int z = rest / nbn;

  const bf16* __restrict__ W = pa.W[z];
  const float* __restrict__ bias = pa.bias[z];
  void* __restrict__ out = pa.out[z];
  const int mode = pa.mode[z];
  const float scale = pa.scale[z];

  const int tid = threadIdx.x;
  const int lane = tid & 63;
  const int w = tid >> 6;          // 0..7
  const int wr = w >> 2;           // 0..1 (M)
  const int wc = w & 3;            // 0..3 (N)
  const int g = lane >> 4, c = lane & 15;

  const int rsub = lane >> 3;                      // 0..7 row within 8-row chunk
  const int csub = ((lane & 7) ^ rsub) * 8;        // inverse-swizzled source col (elems)

  const int arow0 = wr * 128 + wc * 32;            // A rows this wave stages
  const int hb = wc >> 1, gj = (wr << 1) | (wc & 1);
  const int brow0 = hb * 128 + gj * 32;            // B rows this wave stages
  const bf16* Asrc = A + (size_t)(bm * 256 + arow0 + rsub) * 2048 + csub;
  const bf16* Bsrc = W + (size_t)(bn * 256 + brow0 + rsub) * 2048 + csub;

  auto stage = [&](int t, int buf) {
    const int k0 = t * 64;
    char* Adst = (char*)(&As[buf][0]) + arow0 * 128;
    char* Bdst = (char*)(&Bs[buf][0]) + brow0 * 128;
#pragma unroll
    for (int i = 0; i < 4; i++) {
      gload_lds16(Asrc + (size_t)(i * 8) * 2048 + k0, Adst + i * 1024);
      gload_lds16(Bsrc + (size_t)(i * 8) * 2048 + k0, Bdst + i * 1024);
    }
  };

  f32x4 acc[8][4] = {};

  stage(0, 0);
  __syncthreads();
  int cur = 0;

  const int NT = 2048 / 64;
  for (int t = 0; t < NT; t++) {
    if (t + 1 < NT) stage(t + 1, cur ^ 1);   // issue next tile's loads first
#pragma unroll
    for (int kk = 0; kk < 2; kk++) {
      bf16x8 bfr[4], af[8];
#pragma unroll
      for (int n = 0; n < 4; n++) {
        const int row = wc * 64 + n * 16 + c;
        bfr[n] = *(const bf16x8*)((const char*)(&Bs[cur][0]) + row * 128 +
                                  (((kk * 4 + g) ^ (c & 7)) * 16));
      }
#pragma unroll
      for (int mi = 0; mi < 8; mi++) {
        const int row = wr * 128 + mi * 16 + c;
        af[mi] = *(const bf16x8*)((const char*)(&As[cur][0]) + row * 128 +
                                  (((kk * 4 + g) ^ (c & 7)) * 16));
      }
      __builtin_amdgcn_s_setprio(1);
#pragma unroll
      for (int mi = 0; mi < 8; mi++)
#pragma unroll
        for (int n = 0; n < 4; n++)
          acc[mi][n] = __builtin_amdgcn_mfma_f32_16x16x32_bf16(af[mi], bfr[n], acc[mi][n], 0, 0, 0);
      __builtin_amdgcn_s_setprio(0);
    }
    __syncthreads();
    cur ^= 1;
  }

#pragma unroll
  for (int mi = 0; mi < 8; mi++) {
#pragma unroll
    for (int n = 0; n < 4; n++) {
      const int col = bn * 256 + wc * 64 + n * 16 + c;
      const float bv = bias[col];
#pragma unroll
      for (int j = 0; j < 4; j++) {
        const int row = bm * 256 + wr * 128 + mi * 16 + g * 4 + j;
        const float v = (acc[mi][n][j] + bv) * scale;
        if (mode == 0) {
          ((float*)out)[(size_t)row * E_DIM + col] = v;
        } else {
          const int b = row >> 11, s = row & 2047;
          const int h = col >> 7, d = col & 127;
          size_t idx;
          if (mode == 1) idx = (((size_t)(b * HEADS + h)) * SEQ + s) * HD + d;
          else           idx = (((size_t)(b * HEADS + h)) * HD + d) * SEQ + s;
          ((bf16*)out)[idx] = (bf16)v;
        }
      }
    }
  }
}

// ---------------- 128x128 NT GEMM (round-3 version) for the final projection ----------
__global__ __launch_bounds__(256) void gemm_nt_kernel(
    const bf16* __restrict__ A, ProjArgs pa, int M, int N, int K)
{
  __shared__ bf16 As[2][128 * 32];
  __shared__ bf16 Bs[2][128 * 32];

  const int z = blockIdx.z;
  const bf16* __restrict__ W = pa.W[z];
  const float* __restrict__ bias = pa.bias[z];
  void* __restrict__ out = pa.out[z];
  const int mode = pa.mode[z];
  const float scale = pa.scale[z];

  const int tid = threadIdx.x;
  const int lane = tid & 63;
  const int w = tid >> 6;
  const int wr = w >> 1, wc = w & 1;
  const int g = lane >> 4, c = lane & 15;
  const int bm = blockIdx.x, bn = blockIdx.y;

  f32x4 acc[4][4] = {};

  const int srow = lane >> 2;          // 0..15
  const int scol = (lane & 3) * 8;     // 0,8,16,24
  const bf16* Ab = A + (size_t)(bm * 128 + srow) * K + scol;
  const bf16* Wb = W + (size_t)(bn * 128 + srow) * K + scol;

  auto stage = [&](int k0, int buf) {
#pragma unroll
    for (int i = 0; i < 2; ++i) {
      const int chunk = w * 2 + i;     // 0..7, each 1024B = 16 rows x 32 cols
      gload_lds16(Ab + (size_t)(chunk * 16) * K + k0, (char*)(&As[buf][0]) + chunk * 1024);
      gload_lds16(Wb + (size_t)(chunk * 16) * K + k0, (char*)(&Bs[buf][0]) + chunk * 1024);
    }
  };

  stage(0, 0);
  __syncthreads();
  int cur = 0;

  for (int k0 = 0; k0 < K; k0 += 32) {
    if (k0 + 32 < K) stage(k0 + 32, cur ^ 1);
    bf16x8 af[4], bfr[4];
#pragma unroll
    for (int m = 0; m < 4; m++)
      af[m] = *(const bf16x8*)(&As[cur][0] + (wr * 64 + m * 16 + c) * 32 + g * 8);
#pragma unroll
    for (int n = 0; n < 4; n++)
      bfr[n] = *(const bf16x8*)(&Bs[cur][0] + (wc * 64 + n * 16 + c) * 32 + g * 8);
#pragma unroll
    for (int m = 0; m < 4; m++)
#pragma unroll
      for (int n = 0; n < 4; n++)
        acc[m][n] = __builtin_amdgcn_mfma_f32_16x16x32_bf16(af[m], bfr[n], acc[m][n], 0, 0, 0);
    __syncthreads();
    cur ^= 1;
  }

#pragma unroll
  for (int m = 0; m < 4; m++) {
#pragma unroll
    for (int n = 0; n < 4; n++) {
      const int col = bn * 128 + wc * 64 + n * 16 + c;
      const float bv = bias[col];
#pragma unroll
      for (int j = 0; j < 4; j++) {
        const int row = bm * 128 + wr * 64 + m * 16 + g * 4 + j;
        const float v = (acc[m][n][j] + bv) * scale;
        if (mode == 0) {
          ((float*)out)[(size_t)row * N + col] = v;
        } else {
          const int b = row >> 11, s = row & 2047;
          const int h = col >> 7, d = col & 127;
          size_t idx;
          if (mode == 1) idx = (((size_t)(b * HEADS + h)) * SEQ + s) * HD + d;
          else           idx = (((size_t)(b * HEADS + h)) * HD + d) * SEQ + s;
          ((bf16*)out)[idx] = (bf16)v;
        }
      }
    }
  }
}

// ---------------- slots projections: tk/tv = slots @ W^T + b, f32 [8][2048] ----------------
__global__ __launch_bounds__(256) void slots_proj_kernel(
    const float* __restrict__ slots,
    const float* __restrict__ Wk, const float* __restrict__ bk,
    const float* __restrict__ Wv, const float* __restrict__ bv,
    float* __restrict__ tk, float* __restrict__ tv)
{
  const int col = blockIdx.x * 256 + threadIdx.x;
  const int slot = blockIdx.y;
  const int mat = blockIdx.z;
  const float* W = mat ? Wv : Wk;
  const float* bias = mat ? bv : bk;
  float* out = mat ? tv : tk;
  const float* xr = slots + (size_t)slot * E_DIM;
  const float* wr = W + (size_t)col * E_DIM;
  float acc = 0.f;
  for (int k = 0; k < E_DIM; k += 4) {
    const f32x4 a = *(const f32x4*)(xr + k);
    const f32x4 b4 = *(const f32x4*)(wr + k);
#pragma unroll
    for (int i = 0; i < 4; i++) acc += a[i] * b4[i];
  }
  out[(size_t)slot * E_DIM + col] = acc + bias[col];
}

// ---------------- flash attention: staged dbuf + deferred per-lane l-sum ----------------
// Q pre-scaled by QSCALE. Q,K: bf16 [B,H,S,D]; Vt: bf16 [B,H,D,S]; out: bf16 [B,S,E].
// 4 waves, 128 q rows (32/wave). KV tile 64, double-buffered, stage-early,
// defer-max (T13). Row-sum kept as per-lane partials (no per-tile shuffles);
// reduced once in the epilogue. Explicit depth-4 max/sum trees.
__global__ __launch_bounds__(256) void flash_attn_kernel(
    const bf16* __restrict__ Qg, const bf16* __restrict__ Kg,
    const bf16* __restrict__ Vtg, bf16* __restrict__ Og)
{
  __shared__ char Ks[2][64 * 256];    // [kv][d] bf16, 256B rows, XOR-swizzled
  __shared__ char Vs[2][128 * 128];   // [d][kv] bf16, 128B rows, XOR-swizzled
  __shared__ char Ps[4][4096];        // per-wave [q32][kv64] bf16, swizzled

  const int orig = blockIdx.x;                 // 512 blocks
  const int logical = (orig & 7) * 64 + (orig >> 3);   // XCD k -> bh in [4k,4k+4)
  const int qt = logical & 15;
  const int bh = logical >> 4;

  const int tid = threadIdx.x;
  const int lane = tid & 63;
  const int w = tid >> 6;
  const int g = lane >> 4, c = lane & 15;
  const int b = bh >> 4, h = bh & 15;
  const int q0 = qt * 128 + w * 32;

  const bf16* Qb = Qg + ((size_t)bh * SEQ + q0) * HD;
  const bf16* Kb = Kg + (size_t)bh * SEQ * HD;
  const bf16* Vb = Vtg + (size_t)bh * HD * SEQ;
  char* Pw = Ps[w];

  auto stage = [&](int kv0, int buf) {
#pragma unroll
    for (int i = 0; i < 4; i++) {
      const int chunk = w * 4 + i;
      const int p = chunk * 1024 + lane * 16;
      {
        const int r = p >> 8;                       // kv row
        const int sl = ((p >> 4) & 15) ^ (r & 7);   // 16B slot within row
        gload_lds16(Kb + (size_t)(kv0 + r) * HD + sl * 8, &Ks[buf][0] + chunk * 1024);
      }
      {
        const int r = p >> 7;                       // d row
        const int sl = ((p >> 4) & 7) ^ (r & 7);
        gload_lds16(Vb + (size_t)r * SEQ + kv0 + sl * 8, &Vs[buf][0] + chunk * 1024);
      }
    }
  };

  // Q fragments (B operand), pre-scaled: qf[kk][n][j] = Q[n*16+c][kk*32+g*8+j]
  bf16x8 qf[4][2];
#pragma unroll
  for (int kk = 0; kk < 4; kk++)
#pragma unroll
    for (int n = 0; n < 2; n++)
      qf[kk][n] = *(const bf16x8*)(Qb + (size_t)(n * 16 + c) * HD + kk * 32 + g * 8);

  stage(0, 0);
  __syncthreads();
  int cur = 0;

  f32x4 acc[2][8] = {};
  float mrun[2] = {-1e30f, -1e30f};
  float lsum[2] = {0.f, 0.f};          // per-lane partial row-sums (reduced at end)

  for (int kv0 = 0; kv0 < SEQ; kv0 += 64) {
    if (kv0 + 64 < SEQ) stage(kv0 + 64, cur ^ 1);   // issue next K/V tile first

    // S^T[kv][q] = K · Q^T  (scores in log2 domain via pre-scaled Q)
    f32x4 st[4][2] = {};
#pragma unroll
    for (int kk = 0; kk < 4; kk++) {
      bf16x8 kf[4];
#pragma unroll
      for (int kfr = 0; kfr < 4; kfr++) {
        const int r = kfr * 16 + c;
        const int sl = (kk * 4 + g) ^ (r & 7);
        kf[kfr] = *(const bf16x8*)(&Ks[cur][0] + r * 256 + sl * 16);
      }
      __builtin_amdgcn_s_setprio(1);
#pragma unroll
      for (int kfr = 0; kfr < 4; kfr++)
#pragma unroll
        for (int n = 0; n < 2; n++)
          st[kfr][n] = __builtin_amdgcn_mfma_f32_16x16x32_bf16(kf[kfr], qf[kk][n], st[kfr][n], 0, 0, 0);
      __builtin_amdgcn_s_setprio(0);
    }

    // online softmax; all 16 values in a lane share q = n*16 + c
    float fsc[2];
    bool anyresc = false;
#pragma unroll
    for (int n = 0; n < 2; n++) {
      // depth-4 max tree over the 16 local values
      float mt[8];
#pragma unroll
      for (int kfr = 0; kfr < 4; kfr++) {
        mt[kfr * 2]     = fmaxf(st[kfr][n][0], st[kfr][n][1]);
        mt[kfr * 2 + 1] = fmaxf(st[kfr][n][2], st[kfr][n][3]);
      }
#pragma unroll
      for (int i = 0; i < 4; i++) mt[i] = fmaxf(mt[i], mt[i + 4]);
      mt[0] = fmaxf(mt[0], mt[2]); mt[1] = fmaxf(mt[1], mt[3]);
      float lm = fmaxf(mt[0], mt[1]);
      lm = fmaxf(lm, __shfl_xor(lm, 16));
      lm = fmaxf(lm, __shfl_xor(lm, 32));
      if (__any(lm > mrun[n] + 8.0f)) {           // wave-uniform
        const float mn = fmaxf(mrun[n], lm);
        fsc[n] = exp2f(mrun[n] - mn);
        mrun[n] = mn;
        anyresc = true;
      } else {
        fsc[n] = 1.0f;                             // P bounded by 2^8, bf16-safe
      }
      // exp + depth-4 sum tree (per-lane only; no cross-lane shuffles here)
      float stt[8];
#pragma unroll
      for (int kfr = 0; kfr < 4; kfr++) {
        float p0 = exp2f(st[kfr][n][0] - mrun[n]);
        float p1 = exp2f(st[kfr][n][1] - mrun[n]);
        float p2 = exp2f(st[kfr][n][2] - mrun[n]);
        float p3 = exp2f(st[kfr][n][3] - mrun[n]);
        st[kfr][n][0] = p0; st[kfr][n][1] = p1; st[kfr][n][2] = p2; st[kfr][n][3] = p3;
        stt[kfr * 2] = p0 + p1; stt[kfr * 2 + 1] = p2 + p3;
      }
#pragma unroll
      for (int i = 0; i < 4; i++) stt[i] += stt[i + 4];
      stt[0] += stt[2]; stt[1] += stt[3];
      lsum[n] = lsum[n] * fsc[n] + (stt[0] + stt[1]);
    }

    // rescale O accumulator only when a max moved (rare after warm-up)
    if (anyresc) {
#pragma unroll
      for (int m = 0; m < 2; m++)
#pragma unroll
        for (int j = 0; j < 4; j++) {
          const float fj = __shfl(fsc[m], (lane & 48) | (g * 4 + j));
#pragma unroll
          for (int n = 0; n < 8; n++) acc[m][n][j] *= fj;
        }
    }

    // write P (bf16) to per-wave LDS [q][kv], swizzled (wave-local)
#pragma unroll
    for (int n = 0; n < 2; n++)
#pragma unroll
      for (int kfr = 0; kfr < 4; kfr++) {
        bf16x4 pk;
#pragma unroll
        for (int j = 0; j < 4; j++) pk[j] = (bf16)st[kfr][n][j];
        const int q = n * 16 + c;
        const int L = q * 128 + kfr * 32 + g * 8;
        *(bf16x4*)(Pw + (L ^ ((q & 7) << 4))) = pk;
      }

    // O += P · V : A = P[q][kv], B = Vt[d][kv]
#pragma unroll
    for (int kk = 0; kk < 2; kk++) {
      bf16x8 pf[2];
#pragma unroll
      for (int m = 0; m < 2; m++) {
        const int q = m * 16 + c;
        const int L = q * 128 + kk * 64 + g * 16;
        pf[m] = *(const bf16x8*)(Pw + (L ^ ((q & 7) << 4)));
      }
      __builtin_amdgcn_s_setprio(1);
#pragma unroll
      for (int n = 0; n < 8; n++) {
        const int d = n * 16 + c;
        const int Lv = d * 128 + kk * 64 + g * 16;
        const bf16x8 vf = *(const bf16x8*)(&Vs[cur][0] + (Lv ^ ((d & 7) << 4)));
#pragma unroll
        for (int m = 0; m < 2; m++)
          acc[m][n] = __builtin_amdgcn_mfma_f32_16x16x32_bf16(pf[m], vf, acc[m][n], 0, 0, 0);
      }
      __builtin_amdgcn_s_setprio(0);
    }

    __syncthreads();   // single barrier per tile: drains staging vmcnt, guards dbuf reuse
    cur ^= 1;
  }

  // epilogue: reduce l across the 4 g-copies once, normalize, write [B,S,E]
  float lrun[2];
#pragma unroll
  for (int n = 0; n < 2; n++) {
    float t = lsum[n];
    t += __shfl_xor(t, 16);
    t += __shfl_xor(t, 32);
    lrun[n] = t;
  }
#pragma unroll
  for (int m = 0; m < 2; m++) {
#pragma unroll
    for (int j = 0; j < 4; j++) {
      const float lb = __shfl(lrun[m], (lane & 48) | (g * 4 + j));
      const float linv = 1.0f / lb;
      const int s = q0 + m * 16 + g * 4 + j;
#pragma unroll
      for (int n = 0; n < 8; n++) {
        const int e = h * HD + n * 16 + c;
        Og[((size_t)b * SEQ + s) * E_DIM + e] = (bf16)(acc[m][n][j] * linv);
      }
    }
  }
}

// ---------------- fused thought cross-attn + LayerNorm ----------------
__global__ __launch_bounds__(256) void thought_ln_kernel(
    const bf16* __restrict__ TQ, const float* __restrict__ TK,
    const float* __restrict__ TV, const bf16* __restrict__ ATT,
    const float* __restrict__ gamma, const float* __restrict__ beta,
    bf16* __restrict__ Y)
{
  __shared__ float wsum[4], wsq[4];
  const int tid = threadIdx.x;
  const int lane = tid & 63;
  const int w = tid >> 6;
  const int tok = blockIdx.x;            // b*SEQ + s
  const int b = tok >> 11, s = tok & 2047;
  const int e0 = tid * 8;
  const int h = e0 >> 7;
  const int d0 = e0 & 127;

  const bf16x8 av = *(const bf16x8*)(ATT + (size_t)tok * E_DIM + e0);
  float v[8];
#pragma unroll
  for (int i = 0; i < 8; i++) v[i] = (float)av[i];

  const bf16x8 qv8 = *(const bf16x8*)(TQ + (((size_t)(b * HEADS + h)) * SEQ + s) * HD + d0);
  float qv[8];
#pragma unroll
  for (int i = 0; i < 8; i++) qv[i] = (float)qv8[i];

  float dts[NSLOT];
#pragma unroll
  for (int sl = 0; sl < NSLOT; sl++) {
    const float* tkr = TK + (size_t)sl * E_DIM + e0;
    const f32x4 k0 = *(const f32x4*)(tkr);
    const f32x4 k1 = *(const f32x4*)(tkr + 4);
    float dp = 0.f;
#pragma unroll
    for (int i = 0; i < 4; i++) dp += qv[i] * k0[i] + qv[4 + i] * k1[i];
    dp += __shfl_xor(dp, 1);
    dp += __shfl_xor(dp, 2);
    dp += __shfl_xor(dp, 4);
    dp += __shfl_xor(dp, 8);
    dts[sl] = dp;
  }
  float mx = dts[0];
#pragma unroll
  for (int sl = 1; sl < NSLOT; sl++) mx = fmaxf(mx, dts[sl]);
  float p[NSLOT], den = 0.f;
#pragma unroll
  for (int sl = 0; sl < NSLOT; sl++) { p[sl] = exp2f(dts[sl] - mx); den += p[sl]; }
  const float dinv = 1.0f / den;
#pragma unroll
  for (int sl = 0; sl < NSLOT; sl++) {
    const float pn = p[sl] * dinv;
    const float* tvr = TV + (size_t)sl * E_DIM + e0;
    const f32x4 v0 = *(const f32x4*)(tvr);
    const f32x4 v1 = *(const f32x4*)(tvr + 4);
#pragma unroll
    for (int i = 0; i < 4; i++) { v[i] += pn * v0[i]; v[4 + i] += pn * v1[i]; }
  }

  float sm = 0.f, sq = 0.f;
#pragma unroll
  for (int i = 0; i < 8; i++) { sm += v[i]; sq += v[i] * v[i]; }
#pragma unroll
  for (int d = 1; d < 64; d <<= 1) { sm += __shfl_xor(sm, d); sq += __shfl_xor(sq, d); }
  if (lane == 0) { wsum[w] = sm; wsq[w] = sq; }
  __syncthreads();
  const float ts = wsum[0] + wsum[1] + wsum[2] + wsum[3];
  const float tq2 = wsq[0] + wsq[1] + wsq[2] + wsq[3];
  const float mean = ts * (1.f / E_DIM);
  const float var = tq2 * (1.f / E_DIM) - mean * mean;
  const float rstd = rsqrtf(var + 1e-5f);
  const f32x4 g0 = *(const f32x4*)(gamma + e0);
  const f32x4 g1 = *(const f32x4*)(gamma + e0 + 4);
  const f32x4 b0 = *(const f32x4*)(beta + e0);
  const f32x4 b1 = *(const f32x4*)(beta + e0 + 4);
  bf16x8 outv;
#pragma unroll
  for (int i = 0; i < 4; i++) {
    outv[i]     = (bf16)((v[i]     - mean) * rstd * g0[i] + b0[i]);
    outv[4 + i] = (bf16)((v[4 + i] - mean) * rstd * g1[i] + b1[i]);
  }
  *(bf16x8*)(Y + (size_t)tok * E_DIM + e0) = outv;
}

extern "C" void kernel_launch(void* const* d_in, const int* in_sizes, int n_in,
                              void* d_out, int out_size, void* d_ws, size_t ws_size,
                              hipStream_t stream) {
  (void)in_sizes; (void)n_in; (void)out_size; (void)ws_size;
  const float* x     = (const float*)d_in[0];
  const float* slots = (const float*)d_in[1];
  const float* Wq  = (const float*)d_in[2];   const float* bq  = (const float*)d_in[3];
  const float* Wk  = (const float*)d_in[4];   const float* bk  = (const float*)d_in[5];
  const float* Wv  = (const float*)d_in[6];   const float* bv  = (const float*)d_in[7];
  const float* Wtq = (const float*)d_in[8];   const float* btq = (const float*)d_in[9];
  const float* Wtk = (const float*)d_in[10];  const float* btk = (const float*)d_in[11];
  const float* Wtv = (const float*)d_in[12];  const float* btv = (const float*)d_in[13];
  const float* Wo  = (const float*)d_in[14];  const float* bo  = (const float*)d_in[15];
  const float* gamma = (const float*)d_in[16];
  const float* beta  = (const float*)d_in[17];

  uint8_t* ws = (uint8_t*)d_ws;
  const size_t BUF  = (size_t)NTOK * E_DIM * sizeof(bf16);    // 16 MiB (activations)
  const size_t WBUF = (size_t)E_DIM * E_DIM * sizeof(bf16);   // 8 MiB (weights)
  bf16* xb   = (bf16*)(ws + 0 * BUF);          // [B,S,E] bf16 x
  bf16* qb   = (bf16*)(ws + 1 * BUF);          // [B,H,S,D] (pre-scaled)
  bf16* kb   = (bf16*)(ws + 2 * BUF);          // [B,H,S,D]
  bf16* vtb  = (bf16*)(ws + 3 * BUF);          // [B,H,D,S]
  bf16* tqb  = (bf16*)(ws + 4 * BUF);          // [B,H,S,D] (pre-scaled)
  bf16* attb = (bf16*)(ws + 5 * BUF);          // [B,S,E] flash output
  bf16* nrmb = qb;                             // alias: qb dead after flash
  uint8_t* wp = ws + 6 * BUF;
  bf16* Wqb  = (bf16*)(wp + 0 * WBUF);
  bf16* Wkb  = (bf16*)(wp + 1 * WBUF);
  bf16* Wvb  = (bf16*)(wp + 2 * WBUF);
  bf16* Wtqb = (bf16*)(wp + 3 * WBUF);
  bf16* Wob  = (bf16*)(wp + 4 * WBUF);
  float* tkb = (float*)(wp + 5 * WBUF);               // [8][E] f32
  float* tvb = (float*)(wp + 5 * WBUF + 128 * 1024);  // [8][E] f32

  // --- convert f32 -> bf16 for MFMA consumers ---
  const int WN8 = E_DIM * E_DIM / 8;   // 524288
  const int XN8 = NTOK * E_DIM / 8;    // 1048576
  cvt_f32_bf16_kernel<<<dim3(2048), 256, 0, stream>>>(x, xb, XN8);
  cvt_f32_bf16_kernel<<<dim3(1024), 256, 0, stream>>>(Wq, Wqb, WN8);
  cvt_f32_bf16_kernel<<<dim3(1024), 256, 0, stream>>>(Wk, Wkb, WN8);
  cvt_f32_bf16_kernel<<<dim3(1024), 256, 0, stream>>>(Wv, Wvb, WN8);
  cvt_f32_bf16_kernel<<<dim3(1024), 256, 0, stream>>>(Wtq, Wtqb, WN8);
  cvt_f32_bf16_kernel<<<dim3(1024), 256, 0, stream>>>(Wo, Wob, WN8);

  // --- projections (Q and TQ pre-scaled by 1/sqrt(D)*log2e) ---
  ProjArgs pa;
  pa.W[0] = Wqb;  pa.bias[0] = bq;  pa.out[0] = qb;  pa.mode[0] = 1; pa.scale[0] = QSCALE;
  pa.W[1] = Wkb;  pa.bias[1] = bk;  pa.out[1] = kb;  pa.mode[1] = 1; pa.scale[1] = 1.0f;
  pa.W[2] = Wvb;  pa.bias[2] = bv;  pa.out[2] = vtb; pa.mode[2] = 2; pa.scale[2] = 1.0f;
  pa.W[3] = Wtqb; pa.bias[3] = btq; pa.out[3] = tqb; pa.mode[3] = 1; pa.scale[3] = QSCALE;
  gemm256_kernel<<<dim3(16 * 8 * 4), 512, 0, stream>>>(xb, pa, 16, 8);

  slots_proj_kernel<<<dim3(E_DIM / 256, NSLOT, 2), 256, 0, stream>>>(
      slots, Wtk, btk, Wtv, btv, tkb, tvb);

  // --- attention streams ---
  flash_attn_kernel<<<dim3((SEQ / 128) * BATCH * HEADS), 256, 0, stream>>>(
      qb, kb, vtb, attb);
  thought_ln_kernel<<<dim3(NTOK), 256, 0, stream>>>(
      tqb, tkb, tvb, attb, gamma, beta, nrmb);

  // --- output projection (f32 out), 128^2 tiles: 512 blocks = 2/CU ---
  ProjArgs po;
  po.W[0] = Wob; po.bias[0] = bo; po.out[0] = d_out; po.mode[0] = 0; po.scale[0] = 1.0f;
  po.W[1] = po.W[2] = po.W[3] = Wob;
  po.bias[1] = po.bias[2] = po.bias[3] = bo;
  po.out[1] = po.out[2] = po.out[3] = d_out;
  po.mode[1] = po.mode[2] = po.mode[3] = 0;
  po.scale[1] = po.scale[2] = po.scale[3] = 1.0f;
  gemm_nt_kernel<<<dim3(NTOK / 128, E_DIM / 128, 1), 256, 0, stream>>>(
      nrmb, po, NTOK, E_DIM, E_DIM);
}

// Round 7
// 455.789 us; speedup vs baseline: 1.5460x; 1.1494x over previous
//
#include <hip/hip_runtime.h>
#include <hip/hip_bf16.h>
#include <stdint.h>

typedef __bf16 bf16;
typedef __bf16 bf16x8 __attribute__((ext_vector_type(8)));
typedef __bf16 bf16x4 __attribute__((ext_vector_type(4)));
typedef float f32x4 __attribute__((ext_vector_type(4)));
typedef float f32x16 __attribute__((ext_vector_type(16)));
typedef uint32_t u32x2 __attribute__((ext_vector_type(2)));
typedef uint32_t u32x4 __attribute__((ext_vector_type(4)));

#define E_DIM 2048
#define HEADS 16
#define HD 128
#define SEQ 2048
#define BATCH 2
#define NTOK 4096
#define NSLOT 8

// 1/sqrt(128) * log2(e): folded into Q / TQ at projection time
#define QSCALE (0.08838834764831845f * 1.4426950408889634f)

__device__ __forceinline__ void gload_lds16(const void* g, void* lds) {
  __builtin_amdgcn_global_load_lds(
      (const __attribute__((address_space(1))) uint32_t*)g,
      (__attribute__((address_space(3))) uint32_t*)lds, 16, 0, 0);
}

// ---------------- f32 -> bf16 convert, 8 elems/thread, grid-stride ----------------
__global__ __launch_bounds__(256) void cvt_f32_bf16_kernel(
    const float* __restrict__ src, bf16* __restrict__ dst, int n8)
{
  for (int i = blockIdx.x * 256 + threadIdx.x; i < n8; i += gridDim.x * 256) {
    const f32x4 a = *(const f32x4*)(src + i * 8);
    const f32x4 b = *(const f32x4*)(src + i * 8 + 4);
    bf16x8 o;
#pragma unroll
    for (int j = 0; j < 4; j++) { o[j] = (bf16)a[j]; o[4 + j] = (bf16)b[j]; }
    *(bf16x8*)(dst + i * 8) = o;
  }
}

struct ProjArgs {
  const bf16* W[4];
  const float* bias[4];
  void* out[4];
  int mode[4];     // 0: f32 row-major [M][N=2048]; 1: bf16 [B,H,S,D]; 2: bf16 [B,H,D,S]
  float scale[4];  // applied AFTER bias
};

// ---------------- 256x256 NT GEMM, BK=64, 8 waves (round-4/6 measured-good) ---------
__global__ __launch_bounds__(512, 2) void gemm256_kernel(
    const bf16* __restrict__ A, ProjArgs pa, int nbm, int nbn)
{
  __shared__ bf16 As[2][256 * 64];
  __shared__ bf16 Bs[2][256 * 64];

  const int nwg = gridDim.x;
  const int qch = nwg >> 3;
  const int wg = (blockIdx.x & 7) * qch + (blockIdx.x >> 3);
  const int bm = wg % nbm;
  const int rest = wg / nbm;
  const int bn = rest % nbn;
  const int z = rest / nbn;

  const bf16* __restrict__ W = pa.W[z];
  const float* __restrict__ bias = pa.bias[z];
  void* __restrict__ out = pa.out[z];
  const int mode = pa.mode[z];
  const float scale = pa.scale[z];

  const int tid = threadIdx.x;
  const int lane = tid & 63;
  const int w = tid >> 6;          // 0..7
  const int wr = w >> 2;           // 0..1 (M)
  const int wc = w & 3;            // 0..3 (N)
  const int g = lane >> 4, c = lane & 15;

  const int rsub = lane >> 3;                      // 0..7 row within 8-row chunk
  const int csub = ((lane & 7) ^ rsub) * 8;        // inverse-swizzled source col (elems)

  const int arow0 = wr * 128 + wc * 32;            // A rows this wave stages
  const int hb = wc >> 1, gj = (wr << 1) | (wc & 1);
  const int brow0 = hb * 128 + gj * 32;            // B rows this wave stages
  const bf16* Asrc = A + (size_t)(bm * 256 + arow0 + rsub) * 2048 + csub;
  const bf16* Bsrc = W + (size_t)(bn * 256 + brow0 + rsub) * 2048 + csub;

  auto stage = [&](int t, int buf) {
    const int k0 = t * 64;
    char* Adst = (char*)(&As[buf][0]) + arow0 * 128;
    char* Bdst = (char*)(&Bs[buf][0]) + brow0 * 128;
#pragma unroll
    for (int i = 0; i < 4; i++) {
      gload_lds16(Asrc + (size_t)(i * 8) * 2048 + k0, Adst + i * 1024);
      gload_lds16(Bsrc + (size_t)(i * 8) * 2048 + k0, Bdst + i * 1024);
    }
  };

  f32x4 acc[8][4] = {};

  stage(0, 0);
  __syncthreads();
  int cur = 0;

  const int NT = 2048 / 64;
  for (int t = 0; t < NT; t++) {
    if (t + 1 < NT) stage(t + 1, cur ^ 1);
#pragma unroll
    for (int kk = 0; kk < 2; kk++) {
      bf16x8 bfr[4], af[8];
#pragma unroll
      for (int n = 0; n < 4; n++) {
        const int row = wc * 64 + n * 16 + c;
        bfr[n] = *(const bf16x8*)((const char*)(&Bs[cur][0]) + row * 128 +
                                  (((kk * 4 + g) ^ (c & 7)) * 16));
      }
#pragma unroll
      for (int mi = 0; mi < 8; mi++) {
        const int row = wr * 128 + mi * 16 + c;
        af[mi] = *(const bf16x8*)((const char*)(&As[cur][0]) + row * 128 +
                                  (((kk * 4 + g) ^ (c & 7)) * 16));
      }
      __builtin_amdgcn_s_setprio(1);
#pragma unroll
      for (int mi = 0; mi < 8; mi++)
#pragma unroll
        for (int n = 0; n < 4; n++)
          acc[mi][n] = __builtin_amdgcn_mfma_f32_16x16x32_bf16(af[mi], bfr[n], acc[mi][n], 0, 0, 0);
      __builtin_amdgcn_s_setprio(0);
    }
    __syncthreads();
    cur ^= 1;
  }

#pragma unroll
  for (int mi = 0; mi < 8; mi++) {
#pragma unroll
    for (int n = 0; n < 4; n++) {
      const int col = bn * 256 + wc * 64 + n * 16 + c;
      const float bv = bias[col];
#pragma unroll
      for (int j = 0; j < 4; j++) {
        const int row = bm * 256 + wr * 128 + mi * 16 + g * 4 + j;
        const float v = (acc[mi][n][j] + bv) * scale;
        if (mode == 0) {
          ((float*)out)[(size_t)row * E_DIM + col] = v;
        } else {
          const int b = row >> 11, s = row & 2047;
          const int h = col >> 7, d = col & 127;
          size_t idx;
          if (mode == 1) idx = (((size_t)(b * HEADS + h)) * SEQ + s) * HD + d;
          else           idx = (((size_t)(b * HEADS + h)) * HD + d) * SEQ + s;
          ((bf16*)out)[idx] = (bf16)v;
        }
      }
    }
  }
}

// ---------------- 128x128 NT GEMM (round-3 version) for the final projection ----------
__global__ __launch_bounds__(256) void gemm_nt_kernel(
    const bf16* __restrict__ A, ProjArgs pa, int M, int N, int K)
{
  __shared__ bf16 As[2][128 * 32];
  __shared__ bf16 Bs[2][128 * 32];

  const int z = blockIdx.z;
  const bf16* __restrict__ W = pa.W[z];
  const float* __restrict__ bias = pa.bias[z];
  void* __restrict__ out = pa.out[z];
  const int mode = pa.mode[z];
  const float scale = pa.scale[z];

  const int tid = threadIdx.x;
  const int lane = tid & 63;
  const int w = tid >> 6;
  const int wr = w >> 1, wc = w & 1;
  const int g = lane >> 4, c = lane & 15;
  const int bm = blockIdx.x, bn = blockIdx.y;

  f32x4 acc[4][4] = {};

  const int srow = lane >> 2;          // 0..15
  const int scol = (lane & 3) * 8;     // 0,8,16,24
  const bf16* Ab = A + (size_t)(bm * 128 + srow) * K + scol;
  const bf16* Wb = W + (size_t)(bn * 128 + srow) * K + scol;

  auto stage = [&](int k0, int buf) {
#pragma unroll
    for (int i = 0; i < 2; ++i) {
      const int chunk = w * 2 + i;     // 0..7, each 1024B = 16 rows x 32 cols
      gload_lds16(Ab + (size_t)(chunk * 16) * K + k0, (char*)(&As[buf][0]) + chunk * 1024);
      gload_lds16(Wb + (size_t)(chunk * 16) * K + k0, (char*)(&Bs[buf][0]) + chunk * 1024);
    }
  };

  stage(0, 0);
  __syncthreads();
  int cur = 0;

  for (int k0 = 0; k0 < K; k0 += 32) {
    if (k0 + 32 < K) stage(k0 + 32, cur ^ 1);
    bf16x8 af[4], bfr[4];
#pragma unroll
    for (int m = 0; m < 4; m++)
      af[m] = *(const bf16x8*)(&As[cur][0] + (wr * 64 + m * 16 + c) * 32 + g * 8);
#pragma unroll
    for (int n = 0; n < 4; n++)
      bfr[n] = *(const bf16x8*)(&Bs[cur][0] + (wc * 64 + n * 16 + c) * 32 + g * 8);
#pragma unroll
    for (int m = 0; m < 4; m++)
#pragma unroll
      for (int n = 0; n < 4; n++)
        acc[m][n] = __builtin_amdgcn_mfma_f32_16x16x32_bf16(af[m], bfr[n], acc[m][n], 0, 0, 0);
    __syncthreads();
    cur ^= 1;
  }

#pragma unroll
  for (int m = 0; m < 4; m++) {
#pragma unroll
    for (int n = 0; n < 4; n++) {
      const int col = bn * 128 + wc * 64 + n * 16 + c;
      const float bv = bias[col];
#pragma unroll
      for (int j = 0; j < 4; j++) {
        const int row = bm * 128 + wr * 64 + m * 16 + g * 4 + j;
        const float v = (acc[m][n][j] + bv) * scale;
        if (mode == 0) {
          ((float*)out)[(size_t)row * N + col] = v;
        } else {
          const int b = row >> 11, s = row & 2047;
          const int h = col >> 7, d = col & 127;
          size_t idx;
          if (mode == 1) idx = (((size_t)(b * HEADS + h)) * SEQ + s) * HD + d;
          else           idx = (((size_t)(b * HEADS + h)) * HD + d) * SEQ + s;
          ((bf16*)out)[idx] = (bf16)v;
        }
      }
    }
  }
}

// ---------------- slots projections: tk/tv = slots @ W^T + b, f32 [8][2048] ----------------
__global__ __launch_bounds__(256) void slots_proj_kernel(
    const float* __restrict__ slots,
    const float* __restrict__ Wk, const float* __restrict__ bk,
    const float* __restrict__ Wv, const float* __restrict__ bv,
    float* __restrict__ tk, float* __restrict__ tv)
{
  const int col = blockIdx.x * 256 + threadIdx.x;
  const int slot = blockIdx.y;
  const int mat = blockIdx.z;
  const float* W = mat ? Wv : Wk;
  const float* bias = mat ? bv : bk;
  float* out = mat ? tv : tk;
  const float* xr = slots + (size_t)slot * E_DIM;
  const float* wr = W + (size_t)col * E_DIM;
  float acc = 0.f;
  for (int k = 0; k < E_DIM; k += 4) {
    const f32x4 a = *(const f32x4*)(xr + k);
    const f32x4 b4 = *(const f32x4*)(wr + k);
#pragma unroll
    for (int i = 0; i < 4; i++) acc += a[i] * b4[i];
  }
  out[(size_t)slot * E_DIM + col] = acc + bias[col];
}

// ---------------- flash attention: 8-wave 32x32 MFMA, in-register softmax ----------------
// Q pre-scaled by QSCALE. Q,K: bf16 [B,H,S,D]; Vt: bf16 [B,H,D,S]; out: bf16 [B,S,E].
// 512 threads = 8 waves; each wave owns 32 q rows (block = 256 q). KV tile 64,
// double-buffered global_load_lds staging, single barrier per tile.
// Swapped QK^T via mfma_32x32x16: S^T[kv][q], one q per lane (col=lane&31) ->
// softmax max = local tree + 1 shfl_xor(32); sum deferred; rescale/normalize
// are per-lane scalars (no broadcasts). P -> PV B-operand via 2 shfl_xor per
// 16-kv chunk (derived from C/D layout row=(r&3)+8*(r>>2)+4*hi).
__global__ __launch_bounds__(512) void flash_attn_kernel(
    const bf16* __restrict__ Qg, const bf16* __restrict__ Kg,
    const bf16* __restrict__ Vtg, bf16* __restrict__ Og)
{
  __shared__ char Ks[2][64 * 256];    // [kv][d] bf16, 256B rows, slot ^= r&15
  __shared__ char Vs[2][128 * 128];   // [d][kv] bf16, 128B rows, slot ^= r&7

  const int orig = blockIdx.x;                 // 256 blocks
  const int logical = (orig & 7) * 32 + (orig >> 3);   // XCD k -> bh in [4k,4k+4)
  const int qt = logical & 7;
  const int bh = logical >> 3;

  const int tid = threadIdx.x;
  const int lane = tid & 63;
  const int w = tid >> 6;          // 0..7
  const int q = lane & 31;
  const int hi = lane >> 5;
  const int b = bh >> 4, h = bh & 15;
  const int q0 = qt * 256 + w * 32;

  const bf16* Qb = Qg + ((size_t)bh * SEQ + q0) * HD;
  const bf16* Kb = Kg + (size_t)bh * SEQ * HD;
  const bf16* Vb = Vtg + (size_t)bh * HD * SEQ;

  // staging: 512 threads x (2 K-chunks + 2 V-chunks) x 16B = 16KB K + 16KB V
  auto stage = [&](int kv0, int buf) {
#pragma unroll
    for (int i = 0; i < 2; i++) {
      const int p = (tid + i * 512) * 16;
      { const int r = p >> 8; const int s16 = (p >> 4) & 15;
        gload_lds16(Kb + (size_t)(kv0 + r) * HD + (s16 ^ (r & 15)) * 8, &Ks[buf][0] + p); }
      { const int r = p >> 7; const int s8 = (p >> 4) & 7;
        gload_lds16(Vb + (size_t)r * SEQ + kv0 + (s8 ^ (r & 7)) * 8, &Vs[buf][0] + p); }
    }
  };

  // Q B-operand fragments: qf[kc][j] = Q[q][kc*16 + 8*hi + j]
  bf16x8 qf[8];
#pragma unroll
  for (int kc = 0; kc < 8; kc++)
    qf[kc] = *(const bf16x8*)(Qb + (size_t)q * HD + kc * 16 + hi * 8);

  stage(0, 0);
  __syncthreads();
  int cur = 0;

  f32x16 o[4] = {};                  // O^T[d][q], 4 d-blocks of 32
  float mrun = -1e30f, lsum = 0.f;

  for (int kv0 = 0; kv0 < SEQ; kv0 += 64) {
    if (kv0 + 64 < SEQ) stage(kv0 + 64, cur ^ 1);

    // S^T[kv][q] = K · Q^T, two 32-kv blocks
    f32x16 st[2] = {};
    __builtin_amdgcn_s_setprio(1);
#pragma unroll
    for (int kc = 0; kc < 8; kc++) {
#pragma unroll
      for (int blk = 0; blk < 2; blk++) {
        const int rt = blk * 32 + q;
        const int sl = (2 * kc + hi) ^ (rt & 15);
        const bf16x8 kf = *(const bf16x8*)(&Ks[cur][0] + rt * 256 + sl * 16);
        st[blk] = __builtin_amdgcn_mfma_f32_32x32x16_bf16(kf, qf[kc], st[blk], 0, 0, 0);
      }
    }
    __builtin_amdgcn_s_setprio(0);

    // softmax: one q per lane; 32 local kv + the 32 in lane^32
    float t[16];
#pragma unroll
    for (int i = 0; i < 16; i++) t[i] = fmaxf(st[0][i], st[1][i]);
#pragma unroll
    for (int s2 = 8; s2 > 0; s2 >>= 1)
#pragma unroll
      for (int i = 0; i < 8; i++) if (i < s2) t[i] = fmaxf(t[i], t[i + s2]);
    float lm = t[0];
    lm = fmaxf(lm, __shfl_xor(lm, 32));

    float fsc = 1.0f;
    if (__any(lm > mrun + 8.0f)) {             // defer-max (T13), wave-uniform
      const float mn = fmaxf(mrun, lm);
      fsc = exp2f(mrun - mn);
      mrun = mn;
#pragma unroll
      for (int db = 0; db < 4; db++)
#pragma unroll
        for (int i = 0; i < 16; i++) o[db][i] *= fsc;
    }

    float ps0 = 0.f, ps1 = 0.f, ps2 = 0.f, ps3 = 0.f;
#pragma unroll
    for (int blk = 0; blk < 2; blk++)
#pragma unroll
      for (int i = 0; i < 16; i += 4) {
        const float p0 = exp2f(st[blk][i]     - mrun);
        const float p1 = exp2f(st[blk][i + 1] - mrun);
        const float p2 = exp2f(st[blk][i + 2] - mrun);
        const float p3 = exp2f(st[blk][i + 3] - mrun);
        st[blk][i] = p0; st[blk][i + 1] = p1; st[blk][i + 2] = p2; st[blk][i + 3] = p3;
        ps0 += p0; ps1 += p1; ps2 += p2; ps3 += p3;
      }
    lsum = lsum * fsc + ((ps0 + ps1) + (ps2 + ps3));

    // P (C-layout) -> PV B-operand fragments: regs 8c+{0..3}=L, 8c+{4..7}=H;
    // j0-3 <- src-half0, j4-7 <- src-half1, both at regs 4*(2c+H_dest)+{0..3}.
    bf16x8 pb[2][2];
#pragma unroll
    for (int blk = 0; blk < 2; blk++)
#pragma unroll
      for (int c = 0; c < 2; c++) {
        bf16x4 Lv, Hv;
#pragma unroll
        for (int i = 0; i < 4; i++) {
          Lv[i] = (bf16)st[blk][8 * c + i];
          Hv[i] = (bf16)st[blk][8 * c + 4 + i];
        }
        const u32x2 Lu = __builtin_bit_cast(u32x2, Lv);
        const u32x2 Hu = __builtin_bit_cast(u32x2, Hv);
        const uint32_t s0 = hi ? Lu.x : Hu.x;     // half1 sends L, half0 sends H
        const uint32_t s1 = hi ? Lu.y : Hu.y;
        const uint32_t x0 = (uint32_t)__shfl_xor((int)s0, 32);
        const uint32_t x1 = (uint32_t)__shfl_xor((int)s1, 32);
        u32x4 bv;
        bv.x = hi ? x0 : Lu.x;
        bv.y = hi ? x1 : Lu.y;
        bv.z = hi ? Hu.x : x0;
        bv.w = hi ? Hu.y : x1;
        pb[blk][c] = __builtin_bit_cast(bf16x8, bv);
      }

    // O^T[d][q] += V^T[d][kv] · P^T[kv][q]
    __builtin_amdgcn_s_setprio(1);
#pragma unroll
    for (int db = 0; db < 4; db++) {
      const int rt = db * 32 + q;
#pragma unroll
      for (int blk = 0; blk < 2; blk++)
#pragma unroll
        for (int c = 0; c < 2; c++) {
          const int sl = (blk * 4 + c * 2 + hi) ^ (rt & 7);
          const bf16x8 vf = *(const bf16x8*)(&Vs[cur][0] + rt * 128 + sl * 16);
          o[db] = __builtin_amdgcn_mfma_f32_32x32x16_bf16(vf, pb[blk][c], o[db], 0, 0, 0);
        }
    }
    __builtin_amdgcn_s_setprio(0);

    __syncthreads();   // drains own staging vmcnt; guards dbuf reuse
    cur ^= 1;
  }

  // epilogue: total l = own + other half; per-lane normalize; vec4 stores
  const float lt = lsum + __shfl_xor(lsum, 32);
  const float linv = 1.0f / lt;
  bf16* Orow = Og + ((size_t)b * SEQ + q0 + q) * E_DIM + h * HD;
#pragma unroll
  for (int db = 0; db < 4; db++)
#pragma unroll
    for (int g4 = 0; g4 < 4; g4++) {
      bf16x4 ov;
#pragma unroll
      for (int i = 0; i < 4; i++) ov[i] = (bf16)(o[db][g4 * 4 + i] * linv);
      *(bf16x4*)(Orow + db * 32 + g4 * 8 + hi * 4) = ov;
    }
}

// ---------------- fused thought cross-attn + LayerNorm ----------------
__global__ __launch_bounds__(256) void thought_ln_kernel(
    const bf16* __restrict__ TQ, const float* __restrict__ TK,
    const float* __restrict__ TV, const bf16* __restrict__ ATT,
    const float* __restrict__ gamma, const float* __restrict__ beta,
    bf16* __restrict__ Y)
{
  __shared__ float wsum[4], wsq[4];
  const int tid = threadIdx.x;
  const int lane = tid & 63;
  const int w = tid >> 6;
  const int tok = blockIdx.x;            // b*SEQ + s
  const int b = tok >> 11, s = tok & 2047;
  const int e0 = tid * 8;
  const int h = e0 >> 7;
  const int d0 = e0 & 127;

  const bf16x8 av = *(const bf16x8*)(ATT + (size_t)tok * E_DIM + e0);
  float v[8];
#pragma unroll
  for (int i = 0; i < 8; i++) v[i] = (float)av[i];

  const bf16x8 qv8 = *(const bf16x8*)(TQ + (((size_t)(b * HEADS + h)) * SEQ + s) * HD + d0);
  float qv[8];
#pragma unroll
  for (int i = 0; i < 8; i++) qv[i] = (float)qv8[i];

  float dts[NSLOT];
#pragma unroll
  for (int sl = 0; sl < NSLOT; sl++) {
    const float* tkr = TK + (size_t)sl * E_DIM + e0;
    const f32x4 k0 = *(const f32x4*)(tkr);
    const f32x4 k1 = *(const f32x4*)(tkr + 4);
    float dp = 0.f;
#pragma unroll
    for (int i = 0; i < 4; i++) dp += qv[i] * k0[i] + qv[4 + i] * k1[i];
    dp += __shfl_xor(dp, 1);
    dp += __shfl_xor(dp, 2);
    dp += __shfl_xor(dp, 4);
    dp += __shfl_xor(dp, 8);
    dts[sl] = dp;
  }
  float mx = dts[0];
#pragma unroll
  for (int sl = 1; sl < NSLOT; sl++) mx = fmaxf(mx, dts[sl]);
  float p[NSLOT], den = 0.f;
#pragma unroll
  for (int sl = 0; sl < NSLOT; sl++) { p[sl] = exp2f(dts[sl] - mx); den += p[sl]; }
  const float dinv = 1.0f / den;
#pragma unroll
  for (int sl = 0; sl < NSLOT; sl++) {
    const float pn = p[sl] * dinv;
    const float* tvr = TV + (size_t)sl * E_DIM + e0;
    const f32x4 v0 = *(const f32x4*)(tvr);
    const f32x4 v1 = *(const f32x4*)(tvr + 4);
#pragma unroll
    for (int i = 0; i < 4; i++) { v[i] += pn * v0[i]; v[4 + i] += pn * v1[i]; }
  }

  float sm = 0.f, sq = 0.f;
#pragma unroll
  for (int i = 0; i < 8; i++) { sm += v[i]; sq += v[i] * v[i]; }
#pragma unroll
  for (int d = 1; d < 64; d <<= 1) { sm += __shfl_xor(sm, d); sq += __shfl_xor(sq, d); }
  if (lane == 0) { wsum[w] = sm; wsq[w] = sq; }
  __syncthreads();
  const float ts = wsum[0] + wsum[1] + wsum[2] + wsum[3];
  const float tq2 = wsq[0] + wsq[1] + wsq[2] + wsq[3];
  const float mean = ts * (1.f / E_DIM);
  const float var = tq2 * (1.f / E_DIM) - mean * mean;
  const float rstd = rsqrtf(var + 1e-5f);
  const f32x4 g0 = *(const f32x4*)(gamma + e0);
  const f32x4 g1 = *(const f32x4*)(gamma + e0 + 4);
  const f32x4 b0 = *(const f32x4*)(beta + e0);
  const f32x4 b1 = *(const f32x4*)(beta + e0 + 4);
  bf16x8 outv;
#pragma unroll
  for (int i = 0; i < 4; i++) {
    outv[i]     = (bf16)((v[i]     - mean) * rstd * g0[i] + b0[i]);
    outv[4 + i] = (bf16)((v[4 + i] - mean) * rstd * g1[i] + b1[i]);
  }
  *(bf16x8*)(Y + (size_t)tok * E_DIM + e0) = outv;
}

extern "C" void kernel_launch(void* const* d_in, const int* in_sizes, int n_in,
                              void* d_out, int out_size, void* d_ws, size_t ws_size,
                              hipStream_t stream) {
  (void)in_sizes; (void)n_in; (void)out_size; (void)ws_size;
  const float* x     = (const float*)d_in[0];
  const float* slots = (const float*)d_in[1];
  const float* Wq  = (const float*)d_in[2];   const float* bq  = (const float*)d_in[3];
  const float* Wk  = (const float*)d_in[4];   const float* bk  = (const float*)d_in[5];
  const float* Wv  = (const float*)d_in[6];   const float* bv  = (const float*)d_in[7];
  const float* Wtq = (const float*)d_in[8];   const float* btq = (const float*)d_in[9];
  const float* Wtk = (const float*)d_in[10];  const float* btk = (const float*)d_in[11];
  const float* Wtv = (const float*)d_in[12];  const float* btv = (const float*)d_in[13];
  const float* Wo  = (const float*)d_in[14];  const float* bo  = (const float*)d_in[15];
  const float* gamma = (const float*)d_in[16];
  const float* beta  = (const float*)d_in[17];

  uint8_t* ws = (uint8_t*)d_ws;
  const size_t BUF  = (size_t)NTOK * E_DIM * sizeof(bf16);    // 16 MiB (activations)
  const size_t WBUF = (size_t)E_DIM * E_DIM * sizeof(bf16);   // 8 MiB (weights)
  bf16* xb   = (bf16*)(ws + 0 * BUF);          // [B,S,E] bf16 x
  bf16* qb   = (bf16*)(ws + 1 * BUF);          // [B,H,S,D] (pre-scaled)
  bf16* kb   = (bf16*)(ws + 2 * BUF);          // [B,H,S,D]
  bf16* vtb  = (bf16*)(ws + 3 * BUF);          // [B,H,D,S]
  bf16* tqb  = (bf16*)(ws + 4 * BUF);          // [B,H,S,D] (pre-scaled)
  bf16* attb = (bf16*)(ws + 5 * BUF);          // [B,S,E] flash output
  bf16* nrmb = qb;                             // alias: qb dead after flash
  uint8_t* wp = ws + 6 * BUF;
  bf16* Wqb  = (bf16*)(wp + 0 * WBUF);
  bf16* Wkb  = (bf16*)(wp + 1 * WBUF);
  bf16* Wvb  = (bf16*)(wp + 2 * WBUF);
  bf16* Wtqb = (bf16*)(wp + 3 * WBUF);
  bf16* Wob  = (bf16*)(wp + 4 * WBUF);
  float* tkb = (float*)(wp + 5 * WBUF);               // [8][E] f32
  float* tvb = (float*)(wp + 5 * WBUF + 128 * 1024);  // [8][E] f32

  // --- convert f32 -> bf16 for MFMA consumers ---
  const int WN8 = E_DIM * E_DIM / 8;   // 524288
  const int XN8 = NTOK * E_DIM / 8;    // 1048576
  cvt_f32_bf16_kernel<<<dim3(2048), 256, 0, stream>>>(x, xb, XN8);
  cvt_f32_bf16_kernel<<<dim3(1024), 256, 0, stream>>>(Wq, Wqb, WN8);
  cvt_f32_bf16_kernel<<<dim3(1024), 256, 0, stream>>>(Wk, Wkb, WN8);
  cvt_f32_bf16_kernel<<<dim3(1024), 256, 0, stream>>>(Wv, Wvb, WN8);
  cvt_f32_bf16_kernel<<<dim3(1024), 256, 0, stream>>>(Wtq, Wtqb, WN8);
  cvt_f32_bf16_kernel<<<dim3(1024), 256, 0, stream>>>(Wo, Wob, WN8);

  // --- projections (Q and TQ pre-scaled by 1/sqrt(D)*log2e) ---
  ProjArgs pa;
  pa.W[0] = Wqb;  pa.bias[0] = bq;  pa.out[0] = qb;  pa.mode[0] = 1; pa.scale[0] = QSCALE;
  pa.W[1] = Wkb;  pa.bias[1] = bk;  pa.out[1] = kb;  pa.mode[1] = 1; pa.scale[1] = 1.0f;
  pa.W[2] = Wvb;  pa.bias[2] = bv;  pa.out[2] = vtb; pa.mode[2] = 2; pa.scale[2] = 1.0f;
  pa.W[3] = Wtqb; pa.bias[3] = btq; pa.out[3] = tqb; pa.mode[3] = 1; pa.scale[3] = QSCALE;
  gemm256_kernel<<<dim3(16 * 8 * 4), 512, 0, stream>>>(xb, pa, 16, 8);

  slots_proj_kernel<<<dim3(E_DIM / 256, NSLOT, 2), 256, 0, stream>>>(
      slots, Wtk, btk, Wtv, btv, tkb, tvb);

  // --- attention streams ---
  flash_attn_kernel<<<dim3((SEQ / 256) * BATCH * HEADS), 512, 0, stream>>>(
      qb, kb, vtb, attb);
  thought_ln_kernel<<<dim3(NTOK), 256, 0, stream>>>(
      tqb, tkb, tvb, attb, gamma, beta, nrmb);

  // --- output projection (f32 out), 128^2 tiles: 512 blocks = 2/CU ---
  ProjArgs po;
  po.W[0] = Wob; po.bias[0] = bo; po.out[0] = d_out; po.mode[0] = 0; po.scale[0] = 1.0f;
  po.W[1] = po.W[2] = po.W[3] = Wob;
  po.bias[1] = po.bias[2] = po.bias[3] = bo;
  po.out[1] = po.out[2] = po.out[3] = d_out;
  po.mode[1] = po.mode[2] = po.mode[3] = 0;
  po.scale[1] = po.scale[2] = po.scale[3] = 1.0f;
  gemm_nt_kernel<<<dim3(NTOK / 128, E_DIM / 128, 1), 256, 0, stream>>>(
      nrmb, po, NTOK, E_DIM, E_DIM);
}